// Round 1
// baseline (322.062 us; speedup 1.0000x reference)
//
#include <hip/hip_runtime.h>

// FinePreprocess: bilinear 8x8 crops of 32-channel feature maps at 2048
// sub-pixel track points per view, 16 views.
//
// features      : (1, 16, 32, 512, 512) f32   -> d_in[0]
// sample_points : (1, 16, 2048, 2)      f32   -> d_in[1]  (x, y), interior
// img_idxs      : (1, 16, 2048)         int   -> d_in[2]  (0..15, batch idx)
// out           : (1, 16, 2048, 64, 32) f32   -> d_out
//
// One wave (64 lanes) per track; lane = crop pixel p = cy*8 + cx.
// Loop over 32 channels gathering 4 neighbors each; results staged through
// padded LDS to produce fully coalesced channel-innermost global stores.

#define CROP    8
#define C_CH    32
#define H_DIM   512
#define W_DIM   512
#define HW_SZ   (H_DIM * W_DIM)

__global__ __launch_bounds__(64) void fine_preprocess_kernel(
    const float* __restrict__ feat,   // (16, 32, 512, 512) flattened
    const float* __restrict__ pts,    // (32768, 2)
    const int*   __restrict__ bids,   // (32768,)
    float*       __restrict__ out)    // (32768, 64, 32)
{
    const int t    = blockIdx.x;      // track index: v*2048 + n
    const int lane = threadIdx.x;     // 0..63, pixel p = cy*8 + cx
    const int cy   = lane >> 3;
    const int cx   = lane & 7;

    __shared__ float lds[64 * 33];    // +1 pad per pixel row: conflict-free

    // Block-uniform loads (compiler scalarizes these)
    const float px = pts[2 * t];
    const float py = pts[2 * t + 1];
    const int   b  = bids[t];

    // lin = linspace(-4, 4, 8): -4 + k*(8/7)
    const float step = 8.0f / 7.0f;
    const float X = px + fmaf(step, (float)cx, -4.0f);
    const float Y = py + fmaf(step, (float)cy, -4.0f);

    const float x0f = floorf(X);
    const float y0f = floorf(Y);
    const float wx  = X - x0f;
    const float wy  = Y - y0f;
    const int   x0  = (int)x0f;
    const int   y0  = (int)y0f;
    const int   x1  = x0 + 1;
    const int   y1  = y0 + 1;

    // Validity masks (points are interior so these are 1.0, but keep exact
    // reference semantics); folded into the 4 bilinear weights for free.
    const float my0 = (y0 >= 0 && y0 < H_DIM) ? 1.0f : 0.0f;
    const float my1 = (y1 >= 0 && y1 < H_DIM) ? 1.0f : 0.0f;
    const float mx0 = (x0 >= 0 && x0 < W_DIM) ? 1.0f : 0.0f;
    const float mx1 = (x1 >= 0 && x1 < W_DIM) ? 1.0f : 0.0f;

    const int x0c = min(max(x0, 0), W_DIM - 1);
    const int x1c = min(max(x1, 0), W_DIM - 1);
    const int y0c = min(max(y0, 0), H_DIM - 1);
    const int y1c = min(max(y1, 0), H_DIM - 1);

    const float w00 = (1.0f - wy) * (1.0f - wx) * (my0 * mx0);
    const float w01 = (1.0f - wy) * wx          * (my0 * mx1);
    const float w10 = wy          * (1.0f - wx) * (my1 * mx0);
    const float w11 = wy          * wx          * (my1 * mx1);

    // Element offsets into channel-0 plane of view b
    const int plane0 = b * (C_CH * HW_SZ);
    const int r0     = plane0 + y0c * W_DIM;
    const int r1     = plane0 + y1c * W_DIM;
    const int o00 = r0 + x0c;
    const int o01 = r0 + x1c;
    const int o10 = r1 + x0c;
    const int o11 = r1 + x1c;

    #pragma unroll 8
    for (int c = 0; c < C_CH; ++c) {
        const int off = c * HW_SZ;
        const float v00 = feat[o00 + off];
        const float v01 = feat[o01 + off];
        const float v10 = feat[o10 + off];
        const float v11 = feat[o11 + off];
        lds[lane * 33 + c] =
            fmaf(v00, w00, fmaf(v01, w01, fmaf(v10, w10, v11 * w11)));
    }

    __syncthreads();

    // Transposed store phase: element idx within track = p*32 + c, written
    // channel-innermost; consecutive lanes hit consecutive addresses.
    const int obase = t * (CROP * CROP * C_CH);
    #pragma unroll
    for (int k = 0; k < 32; ++k) {
        const int idx = k * 64 + lane;
        out[obase + idx] = lds[(idx >> 5) * 33 + (idx & 31)];
    }
}

extern "C" void kernel_launch(void* const* d_in, const int* in_sizes, int n_in,
                              void* d_out, int out_size, void* d_ws, size_t ws_size,
                              hipStream_t stream) {
    const float* feat = (const float*)d_in[0];
    const float* pts  = (const float*)d_in[1];
    const int*   bids = (const int*)d_in[2];
    float*       out  = (float*)d_out;

    const int n_tracks = in_sizes[2];   // 16 * 2048 = 32768

    fine_preprocess_kernel<<<n_tracks, 64, 0, stream>>>(feat, pts, bids, out);
}